// Round 1
// baseline (257.901 us; speedup 1.0000x reference)
//
#include <hip/hip_runtime.h>

#define IN_DIM 128
#define CAP 64   // per-node bucket capacity; dataset max degree ~ 1+Poisson(15) << 64

__device__ __forceinline__ unsigned short f2bf(float f) {
    unsigned int u = __float_as_uint(f);
    u += 0x7FFFu + ((u >> 16) & 1u);   // round-to-nearest-even
    return (unsigned short)(u >> 16);
}
__device__ __forceinline__ float bf2f(unsigned int lo16) {
    return __uint_as_float(lo16 << 16);
}

__global__ void k_zero(int* __restrict__ p, int n) {
    int i = blockIdx.x * blockDim.x + threadIdx.x;
    if (i < n) p[i] = 0;
}

// Bucket edges by head node; cursor ends up holding the degree.
__global__ void k_scatter(const int* __restrict__ edges, int n_e,
                          int* __restrict__ cursor, int* __restrict__ bucket) {
    int e = blockIdx.x * blockDim.x + threadIdx.x;
    if (e >= n_e) return;
    int h = edges[e];
    int t = edges[n_e + e];
    int pos = atomicAdd(&cursor[h], 1);
    if (pos < CAP) bucket[(size_t)h * CAP + pos] = t;
}

__global__ void k_rsqrt(const int* __restrict__ cursor, float* __restrict__ rsd, int n_n) {
    int i = blockIdx.x * blockDim.x + threadIdx.x;
    if (i >= n_n) return;
    int d = cursor[i];
    rsd[i] = d > 0 ? rsqrtf((float)d) : 0.0f;
}

// Y2[t, :] = bf16( rsd[t] * (X[t, :] @ W^T) ), fp32 accumulate.
// W (128x128 fp32) staged in LDS with XOR swizzle on float4 granules.
// 64 rows/block, thread (tx,ty): rows ty*8..+7, cols {tx, tx+32, tx+64, tx+96}.
__global__ __launch_bounds__(256, 2) void k_gemm(const float* __restrict__ X,
                                                 const float* __restrict__ W,
                                                 const float* __restrict__ rsd,
                                                 unsigned short* __restrict__ Y2, int M) {
    __shared__ float4 Wlds[4096];   // 64 KB, Wlds[c*32 + (k4 ^ (c&7))] = W[c][4k4..4k4+3]
    int tid = threadIdx.x;
    {
        const float4* W4 = (const float4*)W;
        #pragma unroll
        for (int n = 0; n < 16; ++n) {
            int i4 = tid + n * 256;
            int c = i4 >> 5, k4 = i4 & 31;
            Wlds[c * 32 + (k4 ^ (c & 7))] = W4[i4];   // coalesced read, conflict-free write
        }
    }
    __syncthreads();
    int tx = tid & 31, ty = tid >> 5;
    int row0 = blockIdx.x * 64 + ty * 8;
    float acc[8][4] = {};
    for (int k4 = 0; k4 < 32; ++k4) {
        float4 wv[4];
        #pragma unroll
        for (int ci = 0; ci < 4; ++ci) {
            int c = tx + 32 * ci;
            wv[ci] = Wlds[c * 32 + (k4 ^ (c & 7))];
        }
        #pragma unroll
        for (int r = 0; r < 8; ++r) {
            int row = row0 + r;
            int rc = row < M ? row : M - 1;   // clamp tail rows (results discarded)
            float4 xv = *(const float4*)(X + (size_t)rc * IN_DIM + k4 * 4);
            #pragma unroll
            for (int ci = 0; ci < 4; ++ci) {
                acc[r][ci] = fmaf(xv.x, wv[ci].x, acc[r][ci]);
                acc[r][ci] = fmaf(xv.y, wv[ci].y, acc[r][ci]);
                acc[r][ci] = fmaf(xv.z, wv[ci].z, acc[r][ci]);
                acc[r][ci] = fmaf(xv.w, wv[ci].w, acc[r][ci]);
            }
        }
    }
    #pragma unroll
    for (int r = 0; r < 8; ++r) {
        int row = row0 + r;
        if (row >= M) break;
        float s = rsd[row];
        #pragma unroll
        for (int ci = 0; ci < 4; ++ci)
            Y2[(size_t)row * IN_DIM + tx + 32 * ci] = f2bf(acc[r][ci] * s);
    }
}

// One wave per node: gather Y2 rows of its edge targets, sum in fp32,
// apply rsd[h] + ReLU, write 128 floats coalesced.
__global__ __launch_bounds__(256) void k_agg(const unsigned int* __restrict__ Y2u,
                                             const int* __restrict__ bucket,
                                             const int* __restrict__ cursor,
                                             const float* __restrict__ rsd,
                                             float2* __restrict__ out, int n_n) {
    int gw = (int)((blockIdx.x * 256u + threadIdx.x) >> 6);
    int lane = threadIdx.x & 63;
    if (gw >= n_n) return;
    int d = cursor[gw];
    d = d < CAP ? d : CAP;
    const int* bk = bucket + (size_t)gw * CAP;
    int tl = bk[lane];   // lane e holds target of edge e (garbage for e>=d, never used)
    float a0 = 0.f, a1 = 0.f;
    int e = 0;
    for (; e + 4 <= d; e += 4) {   // 4 gathers in flight
        int t0 = __shfl(tl, e);
        int t1 = __shfl(tl, e + 1);
        int t2 = __shfl(tl, e + 2);
        int t3 = __shfl(tl, e + 3);
        unsigned int v0 = Y2u[(size_t)t0 * 64 + lane];
        unsigned int v1 = Y2u[(size_t)t1 * 64 + lane];
        unsigned int v2 = Y2u[(size_t)t2 * 64 + lane];
        unsigned int v3 = Y2u[(size_t)t3 * 64 + lane];
        a0 += bf2f(v0 & 0xFFFFu); a1 += bf2f(v0 >> 16);
        a0 += bf2f(v1 & 0xFFFFu); a1 += bf2f(v1 >> 16);
        a0 += bf2f(v2 & 0xFFFFu); a1 += bf2f(v2 >> 16);
        a0 += bf2f(v3 & 0xFFFFu); a1 += bf2f(v3 >> 16);
    }
    for (; e < d; ++e) {
        int t = __shfl(tl, e);
        unsigned int v = Y2u[(size_t)t * 64 + lane];
        a0 += bf2f(v & 0xFFFFu); a1 += bf2f(v >> 16);
    }
    float s = rsd[gw];
    out[(size_t)gw * 64 + lane] = make_float2(fmaxf(a0 * s, 0.f), fmaxf(a1 * s, 0.f));
}

extern "C" void kernel_launch(void* const* d_in, const int* in_sizes, int n_in,
                              void* d_out, int out_size, void* d_ws, size_t ws_size,
                              hipStream_t stream) {
    const float* X = (const float*)d_in[0];
    const int* edges = (const int*)d_in[1];
    const float* W = (const float*)d_in[2];
    int n_n = in_sizes[0] / IN_DIM;
    int n_e = in_sizes[1] / 2;

    char* ws = (char*)d_ws;
    size_t o = 0;
    auto take = [&](size_t bytes) -> char* {
        char* p = ws + o;
        o += (bytes + 511) & ~(size_t)511;
        return p;
    };
    int* cursor = (int*)take((size_t)n_n * 4);                       // 400 KB
    float* rsd = (float*)take((size_t)n_n * 4);                      // 400 KB
    int* bucket = (int*)take((size_t)n_n * CAP * 4);                 // 25.6 MB
    unsigned short* Y2 = (unsigned short*)take((size_t)n_n * IN_DIM * 2); // 25.6 MB

    k_zero<<<(n_n + 255) / 256, 256, 0, stream>>>(cursor, n_n);
    k_scatter<<<(n_e + 255) / 256, 256, 0, stream>>>(edges, n_e, cursor, bucket);
    k_rsqrt<<<(n_n + 255) / 256, 256, 0, stream>>>(cursor, rsd, n_n);
    k_gemm<<<(n_n + 63) / 64, 256, 0, stream>>>(X, W, rsd, Y2, n_n);
    k_agg<<<(n_n + 3) / 4, 256, 0, stream>>>((const unsigned int*)Y2, bucket, cursor, rsd,
                                             (float2*)d_out, n_n);
}

// Round 2
// 181.116 us; speedup vs baseline: 1.4240x; 1.4240x over previous
//
#include <hip/hip_runtime.h>

#define IN_DIM 128
#define CAP 64          // per-node bucket capacity; dataset max degree ~ 1+Poisson(15) << 64
#define NODE_SHIFT 9    // 512 nodes per coarse bin
#define BIN_NODES (1 << NODE_SHIFT)
#define NB_MAX 256      // supports n_n up to 131072
#define BCAP 12288      // pairs per bin; expected ~8170 +- ~100, >40 sigma slack
#define CHUNK 8192      // edges per partition block (64KB LDS staging)

__device__ __forceinline__ unsigned short f2bf(float f) {
    unsigned int u = __float_as_uint(f);
    u += 0x7FFFu + ((u >> 16) & 1u);   // round-to-nearest-even
    return (unsigned short)(u >> 16);
}
__device__ __forceinline__ float bf2f(unsigned int lo16) {
    return __uint_as_float(lo16 << 16);
}

__global__ void k_zero(int* __restrict__ p, int n) {
    int i = blockIdx.x * blockDim.x + threadIdx.x;
    if (i < n) p[i] = 0;
}

// Pass 1: partition edges into coarse bins of 512 head-nodes each.
// LDS-staged, per-(block,bin) contiguous runs -> coalesced full-line writes.
__global__ __launch_bounds__(256) void k_partition(const int* __restrict__ edges, int n_e,
                                                   int nbins,
                                                   unsigned long long* __restrict__ pairs,
                                                   int* __restrict__ bincur) {
    __shared__ unsigned long long sp[CHUNK];   // 64 KB staged (h,t) pairs
    __shared__ int hist[NB_MAX];
    __shared__ int base[NB_MAX];
    int tid = threadIdx.x;
    int e0 = blockIdx.x * CHUNK;
    int nloc = n_e - e0;
    if (nloc > CHUNK) nloc = CHUNK;
    for (int i = tid; i < nbins; i += 256) hist[i] = 0;
    __syncthreads();
    for (int i = tid; i < nloc; i += 256) {
        int h = edges[e0 + i];
        int t = edges[n_e + e0 + i];
        sp[i] = ((unsigned long long)(unsigned int)h << 32) | (unsigned int)t;
        atomicAdd(&hist[h >> NODE_SHIFT], 1);
    }
    __syncthreads();
    for (int b = tid; b < nbins; b += 256) {
        int c = hist[b];
        base[b] = c ? atomicAdd(&bincur[b], c) : 0;
        hist[b] = 0;
    }
    __syncthreads();
    for (int i = tid; i < nloc; i += 256) {
        unsigned long long p = sp[i];
        int b = (int)(p >> (32 + NODE_SHIFT));
        int pos = atomicAdd(&hist[b], 1);
        int g = base[b] + pos;
        if (g < BCAP) pairs[(size_t)b * BCAP + g] = p;
    }
}

// Pass 2: one block per bin. Per-node cursors in LDS (no global atomics),
// bucket writes confined to a 128 KB L2-resident window. Also emits
// degree (capped) and rsd = deg^-1/2 with plain coalesced stores.
__global__ __launch_bounds__(256) void k_binscatter(const unsigned long long* __restrict__ pairs,
                                                    const int* __restrict__ bincur,
                                                    int* __restrict__ bucket,
                                                    int* __restrict__ cursor,
                                                    float* __restrict__ rsd, int n_n) {
    __shared__ int lcur[BIN_NODES];
    int b = blockIdx.x;
    int tid = threadIdx.x;
    for (int i = tid; i < BIN_NODES; i += 256) lcur[i] = 0;
    __syncthreads();
    int n = bincur[b];
    if (n > BCAP) n = BCAP;
    const unsigned long long* pp = pairs + (size_t)b * BCAP;
    int h0 = b << NODE_SHIFT;
    for (int i = tid; i < n; i += 256) {
        unsigned long long p = pp[i];
        int h = (int)(p >> 32);
        int t = (int)(p & 0xffffffffu);
        int pos = atomicAdd(&lcur[h - h0], 1);
        if (pos < CAP) bucket[(size_t)h * CAP + pos] = t;
    }
    __syncthreads();
    for (int i = tid; i < BIN_NODES; i += 256) {
        int h = h0 + i;
        if (h < n_n) {
            int d = lcur[i];
            cursor[h] = d < CAP ? d : CAP;
            rsd[h] = d > 0 ? rsqrtf((float)d) : 0.0f;
        }
    }
}

// Y2[t, :] = bf16( rsd[t] * (X[t, :] @ W^T) ), fp32 accumulate.
// W (128x128 fp32) staged in LDS with XOR swizzle on float4 granules.
__global__ __launch_bounds__(256, 2) void k_gemm(const float* __restrict__ X,
                                                 const float* __restrict__ W,
                                                 const float* __restrict__ rsd,
                                                 unsigned short* __restrict__ Y2, int M) {
    __shared__ float4 Wlds[4096];   // 64 KB, Wlds[c*32 + (k4 ^ (c&7))] = W[c][4k4..4k4+3]
    int tid = threadIdx.x;
    {
        const float4* W4 = (const float4*)W;
        #pragma unroll
        for (int n = 0; n < 16; ++n) {
            int i4 = tid + n * 256;
            int c = i4 >> 5, k4 = i4 & 31;
            Wlds[c * 32 + (k4 ^ (c & 7))] = W4[i4];
        }
    }
    __syncthreads();
    int tx = tid & 31, ty = tid >> 5;
    int row0 = blockIdx.x * 64 + ty * 8;
    float acc[8][4] = {};
    for (int k4 = 0; k4 < 32; ++k4) {
        float4 wv[4];
        #pragma unroll
        for (int ci = 0; ci < 4; ++ci) {
            int c = tx + 32 * ci;
            wv[ci] = Wlds[c * 32 + (k4 ^ (c & 7))];
        }
        #pragma unroll
        for (int r = 0; r < 8; ++r) {
            int row = row0 + r;
            int rc = row < M ? row : M - 1;   // clamp tail rows (results discarded)
            float4 xv = *(const float4*)(X + (size_t)rc * IN_DIM + k4 * 4);
            #pragma unroll
            for (int ci = 0; ci < 4; ++ci) {
                acc[r][ci] = fmaf(xv.x, wv[ci].x, acc[r][ci]);
                acc[r][ci] = fmaf(xv.y, wv[ci].y, acc[r][ci]);
                acc[r][ci] = fmaf(xv.z, wv[ci].z, acc[r][ci]);
                acc[r][ci] = fmaf(xv.w, wv[ci].w, acc[r][ci]);
            }
        }
    }
    #pragma unroll
    for (int r = 0; r < 8; ++r) {
        int row = row0 + r;
        if (row >= M) break;
        float s = rsd[row];
        #pragma unroll
        for (int ci = 0; ci < 4; ++ci)
            Y2[(size_t)row * IN_DIM + tx + 32 * ci] = f2bf(acc[r][ci] * s);
    }
}

// One wave per node: gather Y2 rows of its edge targets, sum in fp32,
// apply rsd[h] + ReLU, write 128 floats coalesced.
__global__ __launch_bounds__(256) void k_agg(const unsigned int* __restrict__ Y2u,
                                             const int* __restrict__ bucket,
                                             const int* __restrict__ cursor,
                                             const float* __restrict__ rsd,
                                             float2* __restrict__ out, int n_n) {
    int gw = (int)((blockIdx.x * 256u + threadIdx.x) >> 6);
    int lane = threadIdx.x & 63;
    if (gw >= n_n) return;
    int d = cursor[gw];
    const int* bk = bucket + (size_t)gw * CAP;
    int tl = bk[lane];   // lane e holds target of edge e (garbage for e>=d, never used)
    float a0 = 0.f, a1 = 0.f;
    int e = 0;
    for (; e + 4 <= d; e += 4) {   // 4 gathers in flight
        int t0 = __shfl(tl, e);
        int t1 = __shfl(tl, e + 1);
        int t2 = __shfl(tl, e + 2);
        int t3 = __shfl(tl, e + 3);
        unsigned int v0 = Y2u[(size_t)t0 * 64 + lane];
        unsigned int v1 = Y2u[(size_t)t1 * 64 + lane];
        unsigned int v2 = Y2u[(size_t)t2 * 64 + lane];
        unsigned int v3 = Y2u[(size_t)t3 * 64 + lane];
        a0 += bf2f(v0 & 0xFFFFu); a1 += bf2f(v0 >> 16);
        a0 += bf2f(v1 & 0xFFFFu); a1 += bf2f(v1 >> 16);
        a0 += bf2f(v2 & 0xFFFFu); a1 += bf2f(v2 >> 16);
        a0 += bf2f(v3 & 0xFFFFu); a1 += bf2f(v3 >> 16);
    }
    for (; e < d; ++e) {
        int t = __shfl(tl, e);
        unsigned int v = Y2u[(size_t)t * 64 + lane];
        a0 += bf2f(v & 0xFFFFu); a1 += bf2f(v >> 16);
    }
    float s = rsd[gw];
    out[(size_t)gw * 64 + lane] = make_float2(fmaxf(a0 * s, 0.f), fmaxf(a1 * s, 0.f));
}

extern "C" void kernel_launch(void* const* d_in, const int* in_sizes, int n_in,
                              void* d_out, int out_size, void* d_ws, size_t ws_size,
                              hipStream_t stream) {
    const float* X = (const float*)d_in[0];
    const int* edges = (const int*)d_in[1];
    const float* W = (const float*)d_in[2];
    int n_n = in_sizes[0] / IN_DIM;
    int n_e = in_sizes[1] / 2;
    int nbins = (n_n + BIN_NODES - 1) >> NODE_SHIFT;   // 196 for n_n=100000

    char* ws = (char*)d_ws;
    size_t o = 0;
    auto take = [&](size_t bytes) -> char* {
        char* p = ws + o;
        o += (bytes + 511) & ~(size_t)511;
        return p;
    };
    int* cursor = (int*)take((size_t)n_n * 4);                        // 400 KB
    float* rsd = (float*)take((size_t)n_n * 4);                       // 400 KB
    int* bucket = (int*)take((size_t)n_n * CAP * 4);                  // 25.6 MB
    // pairs (19.3 MB) aliases Y2's slot: pairs is consumed by k_binscatter
    // before k_gemm writes Y2.
    size_t y2_bytes = (size_t)n_n * IN_DIM * 2;                       // 25.6 MB
    size_t pair_bytes = (size_t)nbins * BCAP * 8;                     // 19.3 MB
    char* big = take(y2_bytes > pair_bytes ? y2_bytes : pair_bytes);
    unsigned short* Y2 = (unsigned short*)big;
    unsigned long long* pairs = (unsigned long long*)big;
    int* bincur = (int*)take((size_t)nbins * 4);

    k_zero<<<(nbins + 255) / 256, 256, 0, stream>>>(bincur, nbins);
    k_partition<<<(n_e + CHUNK - 1) / CHUNK, 256, 0, stream>>>(edges, n_e, nbins, pairs, bincur);
    k_binscatter<<<nbins, 256, 0, stream>>>(pairs, bincur, bucket, cursor, rsd, n_n);
    k_gemm<<<(n_n + 63) / 64, 256, 0, stream>>>(X, W, rsd, Y2, n_n);
    k_agg<<<(n_n + 3) / 4, 256, 0, stream>>>((const unsigned int*)Y2, bucket, cursor, rsd,
                                             (float2*)d_out, n_n);
}

// Round 3
// 135.220 us; speedup vs baseline: 1.9073x; 1.3394x over previous
//
#include <hip/hip_runtime.h>

#define IN_DIM 128
#define CAP 64          // per-node bucket capacity; dataset max degree ~ 1+Poisson(15) << 64
#define NODE_SHIFT 9    // 512 nodes per coarse bin
#define BIN_NODES (1 << NODE_SHIFT)
#define NB_MAX 256      // supports n_n up to 131072
#define BCAP 12288      // pairs per bin; expected ~8170 +- ~100, >40 sigma slack
#define CHUNK 8192      // edges per partition block (64KB LDS staging)

typedef __attribute__((ext_vector_type(8))) short bf16x8;
typedef __attribute__((ext_vector_type(4))) float f32x4;

__device__ __forceinline__ unsigned short f2bf(float f) {
    unsigned int u = __float_as_uint(f);
    u += 0x7FFFu + ((u >> 16) & 1u);   // round-to-nearest-even
    return (unsigned short)(u >> 16);
}
__device__ __forceinline__ float bf2f(unsigned int lo16) {
    return __uint_as_float(lo16 << 16);
}

__global__ void k_zero(int* __restrict__ p, int n) {
    int i = blockIdx.x * blockDim.x + threadIdx.x;
    if (i < n) p[i] = 0;
}

// Pass 1: partition edges into coarse bins of 512 head-nodes each.
__global__ __launch_bounds__(256) void k_partition(const int* __restrict__ edges, int n_e,
                                                   int nbins,
                                                   unsigned long long* __restrict__ pairs,
                                                   int* __restrict__ bincur) {
    __shared__ unsigned long long sp[CHUNK];   // 64 KB staged (h,t) pairs
    __shared__ int hist[NB_MAX];
    __shared__ int base[NB_MAX];
    int tid = threadIdx.x;
    int e0 = blockIdx.x * CHUNK;
    int nloc = n_e - e0;
    if (nloc > CHUNK) nloc = CHUNK;
    for (int i = tid; i < nbins; i += 256) hist[i] = 0;
    __syncthreads();
    for (int i = tid; i < nloc; i += 256) {
        int h = edges[e0 + i];
        int t = edges[n_e + e0 + i];
        sp[i] = ((unsigned long long)(unsigned int)h << 32) | (unsigned int)t;
        atomicAdd(&hist[h >> NODE_SHIFT], 1);
    }
    __syncthreads();
    for (int b = tid; b < nbins; b += 256) {
        int c = hist[b];
        base[b] = c ? atomicAdd(&bincur[b], c) : 0;
        hist[b] = 0;
    }
    __syncthreads();
    for (int i = tid; i < nloc; i += 256) {
        unsigned long long p = sp[i];
        int b = (int)(p >> (32 + NODE_SHIFT));
        int pos = atomicAdd(&hist[b], 1);
        int g = base[b] + pos;
        if (g < BCAP) pairs[(size_t)b * BCAP + g] = p;
    }
}

// Pass 2: one block per bin; per-node cursors in LDS; emits degree + rsd.
__global__ __launch_bounds__(256) void k_binscatter(const unsigned long long* __restrict__ pairs,
                                                    const int* __restrict__ bincur,
                                                    int* __restrict__ bucket,
                                                    int* __restrict__ cursor,
                                                    float* __restrict__ rsd, int n_n) {
    __shared__ int lcur[BIN_NODES];
    int b = blockIdx.x;
    int tid = threadIdx.x;
    for (int i = tid; i < BIN_NODES; i += 256) lcur[i] = 0;
    __syncthreads();
    int n = bincur[b];
    if (n > BCAP) n = BCAP;
    const unsigned long long* pp = pairs + (size_t)b * BCAP;
    int h0 = b << NODE_SHIFT;
    for (int i = tid; i < n; i += 256) {
        unsigned long long p = pp[i];
        int h = (int)(p >> 32);
        int t = (int)(p & 0xffffffffu);
        int pos = atomicAdd(&lcur[h - h0], 1);
        if (pos < CAP) bucket[(size_t)h * CAP + pos] = t;
    }
    __syncthreads();
    for (int i = tid; i < BIN_NODES; i += 256) {
        int h = h0 + i;
        if (h < n_n) {
            int d = lcur[i];
            cursor[h] = d < CAP ? d : CAP;
            rsd[h] = d > 0 ? rsqrtf((float)d) : 0.0f;
        }
    }
}

// Convert W (128x128 fp32, row-major, dot along k) to bf16 in a swizzled
// 16B-granule layout: granule (n, g) -> Wsw[n*16 + (g ^ (n&7))].
__global__ void k_wconv(const float* __restrict__ W, bf16x8* __restrict__ Wsw) {
    int gi = blockIdx.x * 256 + threadIdx.x;
    if (gi >= 2048) return;
    int n = gi >> 4, g = gi & 15;
    const float* wp = W + n * IN_DIM + g * 8;
    float4 a = *(const float4*)wp;
    float4 b = *(const float4*)(wp + 4);
    bf16x8 v;
    v[0] = (short)f2bf(a.x); v[1] = (short)f2bf(a.y);
    v[2] = (short)f2bf(a.z); v[3] = (short)f2bf(a.w);
    v[4] = (short)f2bf(b.x); v[5] = (short)f2bf(b.y);
    v[6] = (short)f2bf(b.z); v[7] = (short)f2bf(b.w);
    Wsw[n * 16 + (g ^ (n & 7))] = v;
}

// Y2[m, :] = bf16( rsd[m] * (X[m, :] @ W^T) ) via bf16 MFMA, fp32 accumulate.
// Swapped operands: D = mfma(Wfrag, Xfrag) so lane holds out[m0+(l&15)]
// [nt*16 + (l>>4)*4 + r], r=0..3 -> 4 consecutive cols of ONE row -> 8B store.
__global__ __launch_bounds__(256) void k_mfma(const float* __restrict__ X,
                                              const bf16x8* __restrict__ Wg,
                                              const float* __restrict__ rsd,
                                              unsigned short* __restrict__ Y2, int M) {
    __shared__ bf16x8 WL[2048];   // 32 KB swizzled bf16 W
    int tid = threadIdx.x;
    for (int i = tid; i < 2048; i += 256) WL[i] = Wg[i];
    __syncthreads();
    int slab = blockIdx.x * 4 + (tid >> 6);
    int m0 = slab * 16;
    if (m0 >= M) return;
    int l = tid & 63;
    int lm = l & 15, lk = l >> 4;
    int row = m0 + lm;
    int rowc = row < M ? row : M - 1;
    // Load + convert 4 K-step X fragments: lane holds X[rowc][ks*32 + lk*8 + 0..7]
    bf16x8 xf[4];
    const float* xbase = X + (size_t)rowc * IN_DIM + lk * 8;
    #pragma unroll
    for (int ks = 0; ks < 4; ++ks) {
        float4 a = *(const float4*)(xbase + ks * 32);
        float4 b = *(const float4*)(xbase + ks * 32 + 4);
        bf16x8 v;
        v[0] = (short)f2bf(a.x); v[1] = (short)f2bf(a.y);
        v[2] = (short)f2bf(a.z); v[3] = (short)f2bf(a.w);
        v[4] = (short)f2bf(b.x); v[5] = (short)f2bf(b.y);
        v[6] = (short)f2bf(b.z); v[7] = (short)f2bf(b.w);
        xf[ks] = v;
    }
    float s = rsd[rowc];
    #pragma unroll
    for (int nt = 0; nt < 8; ++nt) {
        f32x4 acc = {0.f, 0.f, 0.f, 0.f};
        #pragma unroll
        for (int ks = 0; ks < 4; ++ks) {
            int n = nt * 16 + lm;
            int g = ks * 4 + lk;
            bf16x8 wf = WL[n * 16 + (g ^ (n & 7))];   // 2-way max -> conflict-free
            acc = __builtin_amdgcn_mfma_f32_16x16x32_bf16(wf, xf[ks], acc, 0, 0, 0);
        }
        if (row < M) {
            unsigned int lo = (unsigned int)f2bf(acc[0] * s) |
                              ((unsigned int)f2bf(acc[1] * s) << 16);
            unsigned int hi = (unsigned int)f2bf(acc[2] * s) |
                              ((unsigned int)f2bf(acc[3] * s) << 16);
            uint2* yp = (uint2*)(Y2 + (size_t)row * IN_DIM + nt * 16 + lk * 4);
            *yp = make_uint2(lo, hi);
        }
    }
}

// One wave per node: gather Y2 rows of its edge targets, sum in fp32,
// apply rsd[h] + ReLU, write 128 floats coalesced.
__global__ __launch_bounds__(256) void k_agg(const unsigned int* __restrict__ Y2u,
                                             const int* __restrict__ bucket,
                                             const int* __restrict__ cursor,
                                             const float* __restrict__ rsd,
                                             float2* __restrict__ out, int n_n) {
    int gw = (int)((blockIdx.x * 256u + threadIdx.x) >> 6);
    int lane = threadIdx.x & 63;
    if (gw >= n_n) return;
    int d = cursor[gw];
    const int* bk = bucket + (size_t)gw * CAP;
    int tl = bk[lane];
    float a0 = 0.f, a1 = 0.f;
    int e = 0;
    for (; e + 4 <= d; e += 4) {   // 4 gathers in flight
        int t0 = __shfl(tl, e);
        int t1 = __shfl(tl, e + 1);
        int t2 = __shfl(tl, e + 2);
        int t3 = __shfl(tl, e + 3);
        unsigned int v0 = Y2u[(size_t)t0 * 64 + lane];
        unsigned int v1 = Y2u[(size_t)t1 * 64 + lane];
        unsigned int v2 = Y2u[(size_t)t2 * 64 + lane];
        unsigned int v3 = Y2u[(size_t)t3 * 64 + lane];
        a0 += bf2f(v0 & 0xFFFFu); a1 += bf2f(v0 >> 16);
        a0 += bf2f(v1 & 0xFFFFu); a1 += bf2f(v1 >> 16);
        a0 += bf2f(v2 & 0xFFFFu); a1 += bf2f(v2 >> 16);
        a0 += bf2f(v3 & 0xFFFFu); a1 += bf2f(v3 >> 16);
    }
    for (; e < d; ++e) {
        int t = __shfl(tl, e);
        unsigned int v = Y2u[(size_t)t * 64 + lane];
        a0 += bf2f(v & 0xFFFFu); a1 += bf2f(v >> 16);
    }
    float s = rsd[gw];
    out[(size_t)gw * 64 + lane] = make_float2(fmaxf(a0 * s, 0.f), fmaxf(a1 * s, 0.f));
}

extern "C" void kernel_launch(void* const* d_in, const int* in_sizes, int n_in,
                              void* d_out, int out_size, void* d_ws, size_t ws_size,
                              hipStream_t stream) {
    const float* X = (const float*)d_in[0];
    const int* edges = (const int*)d_in[1];
    const float* W = (const float*)d_in[2];
    int n_n = in_sizes[0] / IN_DIM;
    int n_e = in_sizes[1] / 2;
    int nbins = (n_n + BIN_NODES - 1) >> NODE_SHIFT;   // 196 for n_n=100000

    char* ws = (char*)d_ws;
    size_t o = 0;
    auto take = [&](size_t bytes) -> char* {
        char* p = ws + o;
        o += (bytes + 511) & ~(size_t)511;
        return p;
    };
    int* cursor = (int*)take((size_t)n_n * 4);                        // 400 KB
    float* rsd = (float*)take((size_t)n_n * 4);                       // 400 KB
    int* bucket = (int*)take((size_t)n_n * CAP * 4);                  // 25.6 MB
    // pairs (19.3 MB) aliases Y2's slot: consumed by k_binscatter before k_mfma writes Y2.
    size_t y2_bytes = (size_t)n_n * IN_DIM * 2;                       // 25.6 MB
    size_t pair_bytes = (size_t)nbins * BCAP * 8;                     // 19.3 MB
    char* big = take(y2_bytes > pair_bytes ? y2_bytes : pair_bytes);
    unsigned short* Y2 = (unsigned short*)big;
    unsigned long long* pairs = (unsigned long long*)big;
    int* bincur = (int*)take((size_t)nbins * 4);
    bf16x8* Wsw = (bf16x8*)take(2048 * 16);                           // 32 KB

    int nslab = (n_n + 15) / 16;
    k_zero<<<(nbins + 255) / 256, 256, 0, stream>>>(bincur, nbins);
    k_partition<<<(n_e + CHUNK - 1) / CHUNK, 256, 0, stream>>>(edges, n_e, nbins, pairs, bincur);
    k_wconv<<<8, 256, 0, stream>>>(W, Wsw);
    k_binscatter<<<nbins, 256, 0, stream>>>(pairs, bincur, bucket, cursor, rsd, n_n);
    k_mfma<<<(nslab + 3) / 4, 256, 0, stream>>>(X, Wsw, rsd, Y2, n_n);
    k_agg<<<(n_n + 3) / 4, 256, 0, stream>>>((const unsigned int*)Y2, bucket, cursor, rsd,
                                             (float2*)d_out, n_n);
}

// Round 4
// 133.881 us; speedup vs baseline: 1.9263x; 1.0100x over previous
//
#include <hip/hip_runtime.h>

#define IN_DIM 128
#define CAP 64          // per-node bucket capacity; dataset max degree ~ 1+Poisson(15) << 64
#define NODE_SHIFT 9    // 512 nodes per coarse bin
#define BIN_NODES (1 << NODE_SHIFT)
#define NB_MAX 256      // supports n_n up to 131072
#define BCAP 12288      // pairs per bin; expected ~8170 +- ~100, >40 sigma slack
#define CHUNK 8192      // edges per partition block (64KB LDS staging)

typedef __attribute__((ext_vector_type(8))) short bf16x8;
typedef __attribute__((ext_vector_type(4))) float f32x4;
typedef __attribute__((ext_vector_type(2))) float f32x2;

__device__ __forceinline__ unsigned short f2bf(float f) {
    unsigned int u = __float_as_uint(f);
    u += 0x7FFFu + ((u >> 16) & 1u);   // round-to-nearest-even
    return (unsigned short)(u >> 16);
}
__device__ __forceinline__ float bf2f(unsigned int lo16) {
    return __uint_as_float(lo16 << 16);
}

__global__ void k_zero(int* __restrict__ p, int n) {
    int i = blockIdx.x * blockDim.x + threadIdx.x;
    if (i < n) p[i] = 0;
}

// Pass 1: partition edges into coarse bins of 512 head-nodes each.
__global__ __launch_bounds__(256) void k_partition(const int* __restrict__ edges, int n_e,
                                                   int nbins,
                                                   unsigned long long* __restrict__ pairs,
                                                   int* __restrict__ bincur) {
    __shared__ unsigned long long sp[CHUNK];   // 64 KB staged (h,t) pairs
    __shared__ int hist[NB_MAX];
    __shared__ int base[NB_MAX];
    int tid = threadIdx.x;
    int e0 = blockIdx.x * CHUNK;
    int nloc = n_e - e0;
    if (nloc > CHUNK) nloc = CHUNK;
    for (int i = tid; i < nbins; i += 256) hist[i] = 0;
    __syncthreads();
    for (int i = tid; i < nloc; i += 256) {
        int h = edges[e0 + i];
        int t = edges[n_e + e0 + i];
        sp[i] = ((unsigned long long)(unsigned int)h << 32) | (unsigned int)t;
        atomicAdd(&hist[h >> NODE_SHIFT], 1);
    }
    __syncthreads();
    for (int b = tid; b < nbins; b += 256) {
        int c = hist[b];
        base[b] = c ? atomicAdd(&bincur[b], c) : 0;
        hist[b] = 0;
    }
    __syncthreads();
    for (int i = tid; i < nloc; i += 256) {
        unsigned long long p = sp[i];
        int b = (int)(p >> (32 + NODE_SHIFT));
        int pos = atomicAdd(&hist[b], 1);
        int g = base[b] + pos;
        if (g < BCAP) pairs[(size_t)b * BCAP + g] = p;
    }
}

// Pass 2: one block per bin; per-node cursors in LDS; emits degree + rsd.
__global__ __launch_bounds__(256) void k_binscatter(const unsigned long long* __restrict__ pairs,
                                                    const int* __restrict__ bincur,
                                                    int* __restrict__ bucket,
                                                    int* __restrict__ cursor,
                                                    float* __restrict__ rsd, int n_n) {
    __shared__ int lcur[BIN_NODES];
    int b = blockIdx.x;
    int tid = threadIdx.x;
    for (int i = tid; i < BIN_NODES; i += 256) lcur[i] = 0;
    __syncthreads();
    int n = bincur[b];
    if (n > BCAP) n = BCAP;
    const unsigned long long* pp = pairs + (size_t)b * BCAP;
    int h0 = b << NODE_SHIFT;
    for (int i = tid; i < n; i += 256) {
        unsigned long long p = pp[i];
        int h = (int)(p >> 32);
        int t = (int)(p & 0xffffffffu);
        int pos = atomicAdd(&lcur[h - h0], 1);
        if (pos < CAP) bucket[(size_t)h * CAP + pos] = t;
    }
    __syncthreads();
    for (int i = tid; i < BIN_NODES; i += 256) {
        int h = h0 + i;
        if (h < n_n) {
            int d = lcur[i];
            cursor[h] = d < CAP ? d : CAP;
            rsd[h] = d > 0 ? rsqrtf((float)d) : 0.0f;
        }
    }
}

// Convert W (128x128 fp32, row-major, dot along k) to bf16 in a swizzled
// 16B-granule layout: granule (n, g) -> Wsw[n*16 + (g ^ (n&7))].
__global__ void k_wconv(const float* __restrict__ W, bf16x8* __restrict__ Wsw) {
    int gi = blockIdx.x * 256 + threadIdx.x;
    if (gi >= 2048) return;
    int n = gi >> 4, g = gi & 15;
    const float* wp = W + n * IN_DIM + g * 8;
    float4 a = *(const float4*)wp;
    float4 b = *(const float4*)(wp + 4);
    bf16x8 v;
    v[0] = (short)f2bf(a.x); v[1] = (short)f2bf(a.y);
    v[2] = (short)f2bf(a.z); v[3] = (short)f2bf(a.w);
    v[4] = (short)f2bf(b.x); v[5] = (short)f2bf(b.y);
    v[6] = (short)f2bf(b.z); v[7] = (short)f2bf(b.w);
    Wsw[n * 16 + (g ^ (n & 7))] = v;
}

// Y2[m, :] = bf16( rsd[m] * (X[m, :] @ W^T) ) via bf16 MFMA, fp32 accumulate.
__global__ __launch_bounds__(256) void k_mfma(const float* __restrict__ X,
                                              const bf16x8* __restrict__ Wg,
                                              const float* __restrict__ rsd,
                                              unsigned short* __restrict__ Y2, int M) {
    __shared__ bf16x8 WL[2048];   // 32 KB swizzled bf16 W
    int tid = threadIdx.x;
    for (int i = tid; i < 2048; i += 256) WL[i] = Wg[i];
    __syncthreads();
    int slab = blockIdx.x * 4 + (tid >> 6);
    int m0 = slab * 16;
    if (m0 >= M) return;
    int l = tid & 63;
    int lm = l & 15, lk = l >> 4;
    int row = m0 + lm;
    int rowc = row < M ? row : M - 1;
    bf16x8 xf[4];
    const float* xbase = X + (size_t)rowc * IN_DIM + lk * 8;
    #pragma unroll
    for (int ks = 0; ks < 4; ++ks) {
        float4 a = *(const float4*)(xbase + ks * 32);
        float4 b = *(const float4*)(xbase + ks * 32 + 4);
        bf16x8 v;
        v[0] = (short)f2bf(a.x); v[1] = (short)f2bf(a.y);
        v[2] = (short)f2bf(a.z); v[3] = (short)f2bf(a.w);
        v[4] = (short)f2bf(b.x); v[5] = (short)f2bf(b.y);
        v[6] = (short)f2bf(b.z); v[7] = (short)f2bf(b.w);
        xf[ks] = v;
    }
    float s = rsd[rowc];
    #pragma unroll
    for (int nt = 0; nt < 8; ++nt) {
        f32x4 acc = {0.f, 0.f, 0.f, 0.f};
        #pragma unroll
        for (int ks = 0; ks < 4; ++ks) {
            int n = nt * 16 + lm;
            int g = ks * 4 + lk;
            bf16x8 wf = WL[n * 16 + (g ^ (n & 7))];
            acc = __builtin_amdgcn_mfma_f32_16x16x32_bf16(wf, xf[ks], acc, 0, 0, 0);
        }
        if (row < M) {
            unsigned int lo = (unsigned int)f2bf(acc[0] * s) |
                              ((unsigned int)f2bf(acc[1] * s) << 16);
            unsigned int hi = (unsigned int)f2bf(acc[2] * s) |
                              ((unsigned int)f2bf(acc[3] * s) << 16);
            uint2* yp = (uint2*)(Y2 + (size_t)row * IN_DIM + nt * 16 + lk * 4);
            *yp = make_uint2(lo, hi);
        }
    }
}

// One wave per node. readlane -> SGPR target (SALU addressing), 8 loads in
// flight, padding edges point at zeroed dummy row Y2[n_n] (hot L2 line).
// Accumulate 2 dims/lane with one v_pk_add_f32 per gathered dword.
__global__ __launch_bounds__(256) void k_agg(const unsigned int* __restrict__ Y2u,
                                             const int* __restrict__ bucket,
                                             const int* __restrict__ cursor,
                                             const float* __restrict__ rsd,
                                             float2* __restrict__ out, int n_n) {
    int gw = (int)((blockIdx.x * 256u + threadIdx.x) >> 6);
    int lane = threadIdx.x & 63;
    if (gw >= n_n) return;
    int d = cursor[gw];
    int dpad = (d + 7) & ~7;            // d in [1,64] -> dpad in [8,64]
    const int* bk = bucket + (size_t)gw * CAP;
    // lanes >= d point at the zeroed dummy row; predicated read fetches only
    // the bucket lines actually needed.
    int tl = (lane < d) ? bk[lane] : n_n;
    f32x2 acc = {0.f, 0.f};
    for (int e = 0; e < dpad; e += 8) {
        int t[8];
        unsigned int v[8];
        #pragma unroll
        for (int j = 0; j < 8; ++j) t[j] = __builtin_amdgcn_readlane(tl, e + j);
        #pragma unroll
        for (int j = 0; j < 8; ++j) v[j] = Y2u[(size_t)t[j] * 64 + lane];
        #pragma unroll
        for (int j = 0; j < 8; ++j) {
            f32x2 x;
            x[0] = __uint_as_float(v[j] << 16);
            x[1] = __uint_as_float(v[j] & 0xffff0000u);
            asm("v_pk_add_f32 %0, %1, %0" : "+v"(acc) : "v"(x));
        }
    }
    float s = rsd[gw];
    out[(size_t)gw * 64 + lane] = make_float2(fmaxf(acc[0] * s, 0.f), fmaxf(acc[1] * s, 0.f));
}

extern "C" void kernel_launch(void* const* d_in, const int* in_sizes, int n_in,
                              void* d_out, int out_size, void* d_ws, size_t ws_size,
                              hipStream_t stream) {
    const float* X = (const float*)d_in[0];
    const int* edges = (const int*)d_in[1];
    const float* W = (const float*)d_in[2];
    int n_n = in_sizes[0] / IN_DIM;
    int n_e = in_sizes[1] / 2;
    int nbins = (n_n + BIN_NODES - 1) >> NODE_SHIFT;   // 196 for n_n=100000

    char* ws = (char*)d_ws;
    size_t o = 0;
    auto take = [&](size_t bytes) -> char* {
        char* p = ws + o;
        o += (bytes + 511) & ~(size_t)511;
        return p;
    };
    int* cursor = (int*)take((size_t)n_n * 4);                        // 400 KB
    float* rsd = (float*)take((size_t)n_n * 4);                       // 400 KB
    int* bucket = (int*)take((size_t)n_n * CAP * 4);                  // 25.6 MB
    // pairs (19.3 MB) aliases Y2's slot: consumed by k_binscatter before
    // k_mfma writes Y2. Y2 has n_n+1 rows; row n_n (beyond the 19.3 MB pairs
    // region) is the zeroed dummy row for k_agg padding.
    size_t y2_bytes = (size_t)(n_n + 1) * IN_DIM * 2;                 // 25.6 MB
    size_t pair_bytes = (size_t)nbins * BCAP * 8;                     // 19.3 MB
    char* big = take(y2_bytes > pair_bytes ? y2_bytes : pair_bytes);
    unsigned short* Y2 = (unsigned short*)big;
    unsigned long long* pairs = (unsigned long long*)big;
    int* bincur = (int*)take((size_t)nbins * 4);
    bf16x8* Wsw = (bf16x8*)take(2048 * 16);                           // 32 KB

    int nslab = (n_n + 15) / 16;
    k_zero<<<(nbins + 255) / 256, 256, 0, stream>>>(bincur, nbins);
    k_zero<<<1, 256, 0, stream>>>((int*)(Y2 + (size_t)n_n * IN_DIM), IN_DIM / 2);
    k_partition<<<(n_e + CHUNK - 1) / CHUNK, 256, 0, stream>>>(edges, n_e, nbins, pairs, bincur);
    k_wconv<<<8, 256, 0, stream>>>(W, Wsw);
    k_binscatter<<<nbins, 256, 0, stream>>>(pairs, bincur, bucket, cursor, rsd, n_n);
    k_mfma<<<(nslab + 3) / 4, 256, 0, stream>>>(X, Wsw, rsd, Y2, n_n);
    k_agg<<<(n_n + 3) / 4, 256, 0, stream>>>((const unsigned int*)Y2, bucket, cursor, rsd,
                                             (float2*)d_out, n_n);
}